// Round 3
// baseline (847.279 us; speedup 1.0000x reference)
//
#include <hip/hip_runtime.h>
#include <hip/hip_bf16.h>

#define B_ 32
#define S_ 2048
#define D_ 512

typedef __attribute__((ext_vector_type(8))) short bf16x8;   // 8 bf16 = 4 VGPRs
typedef __attribute__((ext_vector_type(4))) float f32x4;    // MFMA 16x16 accumulator
typedef unsigned short ushort_t;

__device__ __forceinline__ float b2f(ushort_t u) {
  union { unsigned int i; float f; } v; v.i = ((unsigned int)u) << 16; return v.f;
}
__device__ __forceinline__ ushort_t f2b(float f) {   // RTNE fp32 -> bf16 bits
  union { float f; unsigned int i; } v; v.f = f;
  return (ushort_t)((v.i + 0x7FFFu + ((v.i >> 16) & 1u)) >> 16);
}

// packed fp32x2 -> bf16x2 (v_cvt_pk_bf16_f32 on gfx950: 1 VALU op for 2 elems)
__device__ __forceinline__ unsigned int pk2(float lo, float hi) {
#if __has_builtin(__builtin_amdgcn_cvt_pk_bf16_f32)
  typedef __attribute__((ext_vector_type(2))) __bf16 v2bf;
  union { v2bf v; unsigned int u; } u;
  u.v = __builtin_amdgcn_cvt_pk_bf16_f32(lo, hi);
  return u.u;
#else
  return (unsigned int)f2b(lo) | ((unsigned int)f2b(hi) << 16);
#endif
}

__device__ __forceinline__ f32x4 mfma16(bf16x8 a, bf16x8 b, f32x4 c) {
  return __builtin_amdgcn_mfma_f32_16x16x32_bf16(a, b, c, 0, 0, 0);
}

// ---------------------------------------------------------------------------
// dtype detection: low half-word of fp32 words is mantissa junk; of bf16 pairs
// it is a plausible bf16. flag: 1 = bf16 storage, 0 = fp32 storage.
// ---------------------------------------------------------------------------
__global__ void detect_kernel(const unsigned int* __restrict__ w, int* __restrict__ flag) {
  __shared__ int cnt;
  if (threadIdx.x == 0) cnt = 0;
  __syncthreads();
  int c = 0;
  #pragma unroll
  for (int i = 0; i < 4; ++i) {
    unsigned int v = w[threadIdx.x + i * 256];
    unsigned int e = (v >> 7) & 0xFFu;
    if (e >= 110u && e <= 140u) ++c;
  }
  atomicAdd(&cnt, c);
  __syncthreads();
  if (threadIdx.x == 0) flag[0] = (cnt > 512) ? 1 : 0;
}

template <int DT>
__device__ __forceinline__ float ldf(const void* p, size_t idx) {
  if constexpr (DT == 0) return ((const float*)p)[idx];
  else                   return b2f(((const ushort_t*)p)[idx]);
}

// ---------------------------------------------------------------------------
// Stage a [128 rows x 64 k] tile (row stride D_=512 elems in global) into LDS
// as two k-subtiles: tile[sub][row][32], 8-elem chunks XOR-swizzled by
// ((row>>1)&3) so read_frag's ds_read_b128 spreads across bank granules.
// Coalesced map: 16 lanes cover one row's 64 floats contiguously (256 B).
// Per thread: 8 x float4 load + 16 pk2 + 8 ds_write_b64.
// ---------------------------------------------------------------------------
template <int DT>
__device__ __forceinline__ void stage64(const void* gv, size_t elem_off,
                                        ushort_t* tile, int tid) {
  const int kk  = tid & 15;            // which 4-elem group within the 64-k row
  const int sub = kk >> 3;             // k sub-tile
  const int c   = (kk >> 1) & 3;       // 8-elem chunk within subtile
  const int p   = (kk & 1) * 4;        // elem offset within chunk
  #pragma unroll
  for (int i = 0; i < 8; ++i) {
    const int r = (tid >> 4) + i * 16;
    const size_t g = elem_off + (size_t)r * D_ + kk * 4;
    uint2 w;
    if constexpr (DT == 0) {
      float4 v = *(const float4*)((const float*)gv + g);
      w.x = pk2(v.x, v.y); w.y = pk2(v.z, v.w);
    } else {
      w = *(const uint2*)((const ushort_t*)gv + g);
    }
    const int swz = (r >> 1) & 3;
    *(uint2*)(tile + ((sub * 128 + r) * 32) + ((c ^ swz) << 3) + p) = w;
  }
}

// read one 8-elem (K=32) MFMA fragment from a [128][32] subtile
__device__ __forceinline__ bf16x8 read_frag(const ushort_t* tile, int row, int quad) {
  int g = quad ^ ((row >> 1) & 3);
  return *(const bf16x8*)(tile + row * 32 + g * 8);
}

// ---------------------------------------------------------------------------
// Kernel 1: gate[b,s] = sigmoid( sum_e (relu(old_x@W1^T + b1) + old_x)*W2 + b2 )
// ---------------------------------------------------------------------------
template <int DT>
__global__ __launch_bounds__(256, 2)
void gate_kernel(const void* __restrict__ old_x, const int* __restrict__ lang,
                 const void* __restrict__ W1, const void* __restrict__ b1,
                 const void* __restrict__ W2, const void* __restrict__ b2,
                 const int* __restrict__ flag, float* __restrict__ gate) {
  if (flag[0] != DT) return;
  const int b    = blockIdx.y;
  const int s0   = blockIdx.x * 128;
  const int tid  = threadIdx.x;
  const int wave = tid >> 6, lane = tid & 63, quad = lane >> 4, ln = lane & 15;
  const int m_off = (wave >> 1) * 64, n_off = (wave & 1) * 64;
  const int lg = lang[b];

  __shared__ __align__(16) ushort_t As[2 * 128 * 32];
  __shared__ __align__(16) ushort_t Bs[2 * 128 * 32];
  __shared__ float b1s[512], w2s[512], logit[128];

  for (int i = tid; i < 512; i += 256) {
    b1s[i] = ldf<DT>(b1, (size_t)lg * 512 + i);
    w2s[i] = ldf<DT>(W2, (size_t)lg * 512 + i);
  }
  if (tid < 128) logit[tid] = 0.f;
  __syncthreads();

  // residual term: sum_e old_x[s,e]*W2[e]  (2 threads per row, 256 e each)
  {
    const int row = tid >> 1, half = tid & 1;
    const size_t off = ((size_t)b * S_ + s0 + row) * D_ + half * 256;
    float ex = 0.f;
    if constexpr (DT == 0) {
      const float4* xr = (const float4*)((const float*)old_x + off);
      #pragma unroll 8
      for (int c = 0; c < 64; ++c) {
        float4 v = xr[c];
        const float* wp = &w2s[half * 256 + c * 4];
        ex += v.x * wp[0] + v.y * wp[1] + v.z * wp[2] + v.w * wp[3];
      }
    } else {
      const ushort_t* xr = (const ushort_t*)old_x + off;
      #pragma unroll 4
      for (int c = 0; c < 32; ++c) {
        bf16x8 v = *(const bf16x8*)(xr + c * 8);
        #pragma unroll
        for (int j = 0; j < 8; ++j)
          ex += b2f((ushort_t)v[j]) * w2s[half * 256 + c * 8 + j];
      }
    }
    atomicAdd(&logit[row], ex);
  }

  const size_t Aoff = ((size_t)b * S_ + s0) * D_;
  float logacc[16];
  #pragma unroll
  for (int i = 0; i < 16; ++i) logacc[i] = 0.f;

  for (int et = 0; et < 4; ++et) {
    const int e0 = et * 128;
    const size_t Boff = ((size_t)lg * D_ + e0) * D_;
    f32x4 acc[16];
    #pragma unroll
    for (int i = 0; i < 16; ++i) { f32x4 z = {0.f, 0.f, 0.f, 0.f}; acc[i] = z; }

    for (int k0 = 0; k0 < D_; k0 += 64) {
      __syncthreads();
      stage64<DT>(old_x, Aoff + k0, As, tid);
      stage64<DT>(W1,   Boff + k0, Bs, tid);
      __syncthreads();
      #pragma unroll
      for (int j = 0; j < 2; ++j) {
        const ushort_t* Aj = As + j * 128 * 32;
        const ushort_t* Bj = Bs + j * 128 * 32;
        bf16x8 af[4], bfr[4];
        #pragma unroll
        for (int mf = 0; mf < 4; ++mf) af[mf]  = read_frag(Aj, m_off + mf * 16 + ln, quad);
        #pragma unroll
        for (int nf = 0; nf < 4; ++nf) bfr[nf] = read_frag(Bj, n_off + nf * 16 + ln, quad);
        #pragma unroll
        for (int mf = 0; mf < 4; ++mf)
          #pragma unroll
          for (int nf = 0; nf < 4; ++nf)
            acc[mf * 4 + nf] = mfma16(af[mf], bfr[nf], acc[mf * 4 + nf]);
      }
    }
    // fused epilogue: relu(acc+b1)*W2, accumulate per-row partials
    #pragma unroll
    for (int nf = 0; nf < 4; ++nf) {
      int e = e0 + n_off + nf * 16 + ln;
      float b1v = b1s[e], w2v = w2s[e];
      #pragma unroll
      for (int mf = 0; mf < 4; ++mf)
        #pragma unroll
        for (int r = 0; r < 4; ++r) {
          float v = acc[mf * 4 + nf][r] + b1v;
          logacc[mf * 4 + r] += fmaxf(v, 0.f) * w2v;
        }
    }
  }

  #pragma unroll
  for (int off = 1; off < 16; off <<= 1)
    #pragma unroll
    for (int i = 0; i < 16; ++i)
      logacc[i] += __shfl_xor(logacc[i], off, 64);
  if (ln == 0) {
    #pragma unroll
    for (int mf = 0; mf < 4; ++mf)
      #pragma unroll
      for (int r = 0; r < 4; ++r)
        atomicAdd(&logit[m_off + mf * 16 + quad * 4 + r], logacc[mf * 4 + r]);
  }
  __syncthreads();
  if (tid < 128) {
    float l = logit[tid] + ldf<DT>(b2, lg);
    gate[(size_t)b * S_ + s0 + tid] = 1.f / (1.f + expf(-l));
  }
}

// ---------------------------------------------------------------------------
// Kernel 2: out = (1-g)*x@share_W^T + g*x@langs_W[lang]^T
// 1D grid, XCD swizzle: the 4 e-tiles of one (b,s0) get ids differing by 8
// so they land on the same XCD (round-robin id%8) and share the x tile in L2.
// ---------------------------------------------------------------------------
template <int DT>
__global__ __launch_bounds__(256, 2)
void out_kernel(const void* __restrict__ x, const int* __restrict__ lang,
                const void* __restrict__ shareW, const void* __restrict__ langsW,
                const float* __restrict__ gate, const int* __restrict__ flag,
                void* __restrict__ out) {
  if (flag[0] != DT) return;
  const int id = blockIdx.x;
  const int e0 = ((id >> 3) & 3) * 128;
  const int sb = (id >> 5) * 8 + (id & 7);      // [0,512): b*16 + s-tile
  const int b  = sb >> 4;
  const int s0 = (sb & 15) * 128;
  const int tid  = threadIdx.x;
  const int wave = tid >> 6, lane = tid & 63, quad = lane >> 4, ln = lane & 15;
  const int m_off = (wave >> 1) * 64, n_off = (wave & 1) * 64;
  const int lg = lang[b];

  __shared__ __align__(16) ushort_t As[2 * 128 * 32];
  __shared__ __align__(16) ushort_t Ss[2 * 128 * 32];
  __shared__ __align__(16) ushort_t Ls[2 * 128 * 32];

  const size_t Aoff = ((size_t)b * S_ + s0) * D_;
  const size_t Soff = (size_t)e0 * D_;
  const size_t Loff = ((size_t)lg * D_ + e0) * D_;

  f32x4 accS[16], accL[16];
  #pragma unroll
  for (int i = 0; i < 16; ++i) {
    f32x4 z = {0.f, 0.f, 0.f, 0.f};
    accS[i] = z; accL[i] = z;
  }

  for (int k0 = 0; k0 < D_; k0 += 64) {
    __syncthreads();
    stage64<DT>(x,      Aoff + k0, As, tid);
    stage64<DT>(shareW, Soff + k0, Ss, tid);
    stage64<DT>(langsW, Loff + k0, Ls, tid);
    __syncthreads();
    #pragma unroll
    for (int j = 0; j < 2; ++j) {
      const ushort_t* Aj = As + j * 128 * 32;
      const ushort_t* Sj = Ss + j * 128 * 32;
      const ushort_t* Lj = Ls + j * 128 * 32;
      bf16x8 af[4], sf[4], lf[4];
      #pragma unroll
      for (int mf = 0; mf < 4; ++mf) af[mf] = read_frag(Aj, m_off + mf * 16 + ln, quad);
      #pragma unroll
      for (int nf = 0; nf < 4; ++nf) {
        sf[nf] = read_frag(Sj, n_off + nf * 16 + ln, quad);
        lf[nf] = read_frag(Lj, n_off + nf * 16 + ln, quad);
      }
      #pragma unroll
      for (int mf = 0; mf < 4; ++mf)
        #pragma unroll
        for (int nf = 0; nf < 4; ++nf) {
          accS[mf * 4 + nf] = mfma16(af[mf], sf[nf], accS[mf * 4 + nf]);
          accL[mf * 4 + nf] = mfma16(af[mf], lf[nf], accL[mf * 4 + nf]);
        }
    }
  }

  // epilogue: blend with gate, store per storage dtype
  #pragma unroll
  for (int mf = 0; mf < 4; ++mf) {
    int srow = s0 + m_off + mf * 16 + quad * 4;
    float gv[4];
    #pragma unroll
    for (int r = 0; r < 4; ++r) gv[r] = gate[(size_t)b * S_ + srow + r];
    #pragma unroll
    for (int nf = 0; nf < 4; ++nf) {
      int col = e0 + n_off + nf * 16 + ln;
      f32x4 cs = accS[mf * 4 + nf], cl = accL[mf * 4 + nf];
      #pragma unroll
      for (int r = 0; r < 4; ++r) {
        float v = cs[r] + gv[r] * (cl[r] - cs[r]);
        size_t idx = ((size_t)b * S_ + srow + r) * D_ + col;
        if constexpr (DT == 0) ((float*)out)[idx] = v;
        else                   ((ushort_t*)out)[idx] = f2b(v);
      }
    }
  }
}

extern "C" void kernel_launch(void* const* d_in, const int* in_sizes, int n_in,
                              void* d_out, int out_size, void* d_ws, size_t ws_size,
                              hipStream_t stream) {
  const void* old_x  = d_in[0];
  const void* x      = d_in[1];
  const int*  lang   = (const int*)d_in[2];
  const void* shareW = d_in[3];
  const void* langsW = d_in[4];
  const void* gW1    = d_in[5];
  const void* gb1    = d_in[6];
  const void* gW2    = d_in[7];
  const void* gb2    = d_in[8];

  float* gate = (float*)d_ws;                                   // B*S floats
  int*   flag = (int*)((char*)d_ws + (size_t)B_ * S_ * sizeof(float));

  detect_kernel<<<1, 256, 0, stream>>>((const unsigned int*)old_x, flag);

  dim3 g1(S_ / 128, B_);
  gate_kernel<0><<<g1, dim3(256), 0, stream>>>(old_x, lang, gW1, gb1, gW2, gb2, flag, gate);
  gate_kernel<1><<<g1, dim3(256), 0, stream>>>(old_x, lang, gW1, gb1, gW2, gb2, flag, gate);

  out_kernel<0><<<dim3(2048), dim3(256), 0, stream>>>(x, lang, shareW, langsW, gate, flag, d_out);
  out_kernel<1><<<dim3(2048), dim3(256), 0, stream>>>(x, lang, shareW, langsW, gate, flag, d_out);
}